// Round 1
// baseline (124.779 us; speedup 1.0000x reference)
//
#include <hip/hip_runtime.h>
#include <math.h>

#define B_    8
#define N_    2048
#define FIN   256
#define FO    128
#define ALPHA 0.2f
#define NCHUNK 16
#define CHUNK  128   // N_/NCHUNK

// ---------------- workspace layout (float elements) ----------------
// Wh    : B*N*FO           = 2097152
// Wt    : FO*FIN           = 32768
// s1    : B*N              = 16384
// s2    : B*N              = 16384
// ssort : B*N              = 16384
// sord  : B*N (int)        = 16384
// e2p   : B*N              = 16384
// e2n   : B*N              = 16384
// DP    : B*N              = 16384
// DN    : B*N              = 16384
// SP    : B*N*FO           = 2097152
// SN    : B*N*FO           = 2097152
// offsP : B*NCHUNK*FO      = 16384
// offsN : B*NCHUNK*FO      = 16384
// SNtot : B*FO             = 1024
static const size_t OFF_WH    = 0;
static const size_t OFF_WT    = OFF_WH    + (size_t)B_*N_*FO;
static const size_t OFF_S1    = OFF_WT    + (size_t)FO*FIN;
static const size_t OFF_S2    = OFF_S1    + (size_t)B_*N_;
static const size_t OFF_SSORT = OFF_S2    + (size_t)B_*N_;
static const size_t OFF_SORD  = OFF_SSORT + (size_t)B_*N_;
static const size_t OFF_E2P   = OFF_SORD  + (size_t)B_*N_;
static const size_t OFF_E2N   = OFF_E2P   + (size_t)B_*N_;
static const size_t OFF_DP    = OFF_E2N   + (size_t)B_*N_;
static const size_t OFF_DN    = OFF_DP    + (size_t)B_*N_;
static const size_t OFF_SP    = OFF_DN    + (size_t)B_*N_;
static const size_t OFF_SN    = OFF_SP    + (size_t)B_*N_*FO;
static const size_t OFF_OFFSP = OFF_SN    + (size_t)B_*N_*FO;
static const size_t OFF_OFFSN = OFF_OFFSP + (size_t)B_*NCHUNK*FO;
static const size_t OFF_SNTOT = OFF_OFFSN + (size_t)B_*NCHUNK*FO;

// ---------------- K0: transpose W -> Wt[f][k] ----------------
__global__ void k0_transpose(const float* __restrict__ W, float* __restrict__ Wt) {
    int f = blockIdx.x;    // 0..127
    int k = threadIdx.x;   // 0..255
    Wt[f * FIN + k] = W[k * FO + f];
}

// ---------------- K1: Wh = h @ W  (+ fused s1, s2) ----------------
// grid 256 blocks (64 rows each), 128 threads, 8x8 register tile.
__global__ __launch_bounds__(128) void k1_gemm(const float* __restrict__ h,
                                               const float* __restrict__ Wt,
                                               const float* __restrict__ a,
                                               float* __restrict__ Wh,
                                               float* __restrict__ s1g,
                                               float* __restrict__ s2g) {
    __shared__ __align__(16) float hS[64 * 36];    // [i][k] stride 36
    __shared__ __align__(16) float wS[128 * 36];   // [f][k] stride 36
    __shared__ float red1[64][16];
    __shared__ float red2[64][16];

    const int tid = threadIdx.x;
    const int fg  = tid & 15;   // 16 f-groups, f = fg + 16c
    const int ig  = tid >> 4;   // 8 i-groups,  i = ig + 8r
    const int row0 = blockIdx.x * 64;

    float acc[8][8];
#pragma unroll
    for (int r = 0; r < 8; ++r)
#pragma unroll
        for (int c = 0; c < 8; ++c) acc[r][c] = 0.f;

    for (int kt = 0; kt < FIN; kt += 32) {
        // stage h tile 64x32
#pragma unroll
        for (int p = 0; p < 4; ++p) {
            int idx = p * 128 + tid;
            int ri = idx >> 3, c4 = (idx & 7) * 4;
            *(float4*)&hS[ri * 36 + c4] =
                *(const float4*)&h[(size_t)(row0 + ri) * FIN + kt + c4];
        }
        // stage Wt tile 128x32
#pragma unroll
        for (int p = 0; p < 8; ++p) {
            int idx = p * 128 + tid;
            int f = idx >> 3, c4 = (idx & 7) * 4;
            *(float4*)&wS[f * 36 + c4] =
                *(const float4*)&Wt[f * FIN + kt + c4];
        }
        __syncthreads();

        for (int kk = 0; kk < 32; kk += 4) {
            float4 hf[8], wf[8];
#pragma unroll
            for (int r = 0; r < 8; ++r) hf[r] = *(float4*)&hS[(ig + 8 * r) * 36 + kk];
#pragma unroll
            for (int c = 0; c < 8; ++c) wf[c] = *(float4*)&wS[(fg + 16 * c) * 36 + kk];
#pragma unroll
            for (int r = 0; r < 8; ++r)
#pragma unroll
                for (int c = 0; c < 8; ++c) {
                    acc[r][c] += hf[r].x * wf[c].x;
                    acc[r][c] += hf[r].y * wf[c].y;
                    acc[r][c] += hf[r].z * wf[c].z;
                    acc[r][c] += hf[r].w * wf[c].w;
                }
        }
        __syncthreads();
    }

    // write Wh
#pragma unroll
    for (int r = 0; r < 8; ++r)
#pragma unroll
        for (int c = 0; c < 8; ++c)
            Wh[(size_t)(row0 + ig + 8 * r) * FO + fg + 16 * c] = acc[r][c];

    // fused s1/s2: per-thread partial dot with a1/a2, reduce over 16 f-groups
    float a1v[8], a2v[8];
#pragma unroll
    for (int c = 0; c < 8; ++c) {
        a1v[c] = a[fg + 16 * c];
        a2v[c] = a[FO + fg + 16 * c];
    }
#pragma unroll
    for (int r = 0; r < 8; ++r) {
        float p1 = 0.f, p2 = 0.f;
#pragma unroll
        for (int c = 0; c < 8; ++c) {
            p1 += acc[r][c] * a1v[c];
            p2 += acc[r][c] * a2v[c];
        }
        red1[ig + 8 * r][fg] = p1;
        red2[ig + 8 * r][fg] = p2;
    }
    __syncthreads();
    if (tid < 128) {
        int li = tid & 63, which = tid >> 6;
        float s = 0.f;
        if (which == 0) {
#pragma unroll
            for (int g = 0; g < 16; ++g) s += red1[li][g];
            s1g[row0 + li] = s;
        } else {
#pragma unroll
            for (int g = 0; g < 16; ++g) s += red2[li][g];
            s2g[row0 + li] = s;
        }
    }
}

// ---------------- K2: per-batch sort of s2 (desc) + scalar denom scans ----------------
__global__ __launch_bounds__(1024) void k2_sort(const float* __restrict__ s2g,
                                                float* __restrict__ ssort,
                                                int* __restrict__ sord,
                                                float* __restrict__ e2p,
                                                float* __restrict__ e2n,
                                                float* __restrict__ DP,
                                                float* __restrict__ DN) {
    __shared__ float vals[N_];
    __shared__ int   idxs[N_];
    __shared__ float ep[N_];
    __shared__ float en[N_];
    const int b = blockIdx.x, tid = threadIdx.x;

    for (int t = tid; t < N_; t += 1024) { vals[t] = s2g[b * N_ + t]; idxs[t] = t; }
    __syncthreads();

    // bitonic sort, descending, with index payload
    for (int k = 2; k <= N_; k <<= 1) {
        for (int j = k >> 1; j > 0; j >>= 1) {
            for (int t = tid; t < N_; t += 1024) {
                int ixj = t ^ j;
                if (ixj > t) {
                    float v0 = vals[t], v1 = vals[ixj];
                    bool up = (t & k) == 0;
                    if (up ? (v0 < v1) : (v0 > v1)) {
                        vals[t] = v1; vals[ixj] = v0;
                        int tmp = idxs[t]; idxs[t] = idxs[ixj]; idxs[ixj] = tmp;
                    }
                }
            }
            __syncthreads();
        }
    }

    // write sorted arrays + exps
    for (int t = tid; t < N_; t += 1024) {
        float v = vals[t];
        ssort[b * N_ + t] = v;
        sord[b * N_ + t] = idxs[t];
        float p = expf(v), q = expf(ALPHA * v);
        e2p[b * N_ + t] = p; e2n[b * N_ + t] = q;
        ep[t] = p; en[t] = q;
    }
    __syncthreads();

    // Hillis-Steele inclusive scans of ep/en -> DP/DN
    for (int off = 1; off < N_; off <<= 1) {
        int t0 = tid, t1 = tid + 1024;
        float A0 = ep[t0] + (t0 >= off ? ep[t0 - off] : 0.f);
        float B0 = en[t0] + (t0 >= off ? en[t0 - off] : 0.f);
        float A1 = ep[t1] + (t1 >= off ? ep[t1 - off] : 0.f);
        float B1 = en[t1] + (t1 >= off ? en[t1 - off] : 0.f);
        __syncthreads();
        ep[t0] = A0; en[t0] = B0; ep[t1] = A1; en[t1] = B1;
        __syncthreads();
    }
    DP[b * N_ + tid] = ep[tid];
    DP[b * N_ + tid + 1024] = ep[tid + 1024];
    DN[b * N_ + tid] = en[tid];
    DN[b * N_ + tid + 1024] = en[tid + 1024];
}

// ---------------- K3: chunk-local vector prefix scans ----------------
// grid = B*NCHUNK blocks, 128 threads (one per f)
__global__ __launch_bounds__(128) void k3_scan(const float* __restrict__ Wh,
                                               const int* __restrict__ sord,
                                               const float* __restrict__ e2p,
                                               const float* __restrict__ e2n,
                                               float* __restrict__ SP,
                                               float* __restrict__ SN) {
    const int b = blockIdx.x >> 4, ch = blockIdx.x & 15;
    const int f = threadIdx.x;
    const int k0 = ch * CHUNK;
    float accP = 0.f, accN = 0.f;
#pragma unroll 4
    for (int k = k0; k < k0 + CHUNK; ++k) {
        int ord = sord[b * N_ + k];
        float wp = e2p[b * N_ + k];
        float wn = e2n[b * N_ + k];
        float x = Wh[((size_t)b * N_ + ord) * FO + f];
        accP += wp * x;
        accN += wn * x;
        SP[((size_t)b * N_ + k) * FO + f] = accP;
        SN[((size_t)b * N_ + k) * FO + f] = accN;
    }
}

// ---------------- K3b: exclusive cumsum of chunk totals ----------------
__global__ __launch_bounds__(128) void k3b_offs(const float* __restrict__ SP,
                                                const float* __restrict__ SN,
                                                float* __restrict__ offsP,
                                                float* __restrict__ offsN,
                                                float* __restrict__ SNtot) {
    const int b = blockIdx.x, f = threadIdx.x;
    float rp = 0.f, rn = 0.f;
#pragma unroll
    for (int c = 0; c < NCHUNK; ++c) {
        offsP[(b * NCHUNK + c) * FO + f] = rp;
        offsN[(b * NCHUNK + c) * FO + f] = rn;
        rp += SP[((size_t)b * N_ + c * CHUNK + CHUNK - 1) * FO + f];
        rn += SN[((size_t)b * N_ + c * CHUNK + CHUNK - 1) * FO + f];
    }
    SNtot[b * FO + f] = rn;
}

// ---------------- K4: binary search + combine + elu ----------------
// grid = B*N/2 blocks, 256 threads (2 rows x 128 f)
__global__ __launch_bounds__(256) void k4_final(const float* __restrict__ s1g,
                                                const float* __restrict__ ssort,
                                                const float* __restrict__ DP,
                                                const float* __restrict__ DN,
                                                const float* __restrict__ SP,
                                                const float* __restrict__ SN,
                                                const float* __restrict__ offsP,
                                                const float* __restrict__ offsN,
                                                const float* __restrict__ SNtot,
                                                float* __restrict__ out) {
    const int rowg = blockIdx.x * 2 + (threadIdx.x >> 7);
    const int f = threadIdx.x & 127;
    const int b = rowg >> 11;

    const float s1v = s1g[rowg];
    const float target = -s1v;
    const float* ss = ssort + b * N_;
    int lo = 0, hi = N_;
    while (lo < hi) {
        int mid = (lo + hi) >> 1;
        if (ss[mid] >= target) lo = mid + 1; else hi = mid;
    }
    const int k = lo;   // count of j in positive branch

    const float ep1 = expf(s1v), en1 = expf(ALPHA * s1v);
    float dp = 0.f, dn = 0.f, sp = 0.f, sn = 0.f;
    if (k > 0) {
        dp = DP[b * N_ + k - 1];
        dn = DN[b * N_ + k - 1];
        int c = (k - 1) / CHUNK;
        size_t ro = ((size_t)b * N_ + k - 1) * FO + f;
        sp = offsP[(b * NCHUNK + c) * FO + f] + SP[ro];
        sn = offsN[(b * NCHUNK + c) * FO + f] + SN[ro];
    }
    const float dnt = DN[b * N_ + N_ - 1];
    const float snt = SNtot[b * FO + f];

    const float den = ep1 * dp + en1 * (dnt - dn);
    const float num = ep1 * sp + en1 * (snt - sn);
    const float o = num / den;
    out[(size_t)rowg * FO + f] = (o > 0.f) ? o : (expf(o) - 1.f);
}

// ---------------- launch ----------------
extern "C" void kernel_launch(void* const* d_in, const int* in_sizes, int n_in,
                              void* d_out, int out_size, void* d_ws, size_t ws_size,
                              hipStream_t stream) {
    const float* h = (const float*)d_in[0];
    const float* W = (const float*)d_in[1];
    const float* a = (const float*)d_in[2];
    float* out = (float*)d_out;
    float* ws = (float*)d_ws;

    float* Wh    = ws + OFF_WH;
    float* Wt    = ws + OFF_WT;
    float* s1    = ws + OFF_S1;
    float* s2    = ws + OFF_S2;
    float* ssort = ws + OFF_SSORT;
    int*   sord  = (int*)(ws + OFF_SORD);
    float* e2p   = ws + OFF_E2P;
    float* e2n   = ws + OFF_E2N;
    float* DP    = ws + OFF_DP;
    float* DN    = ws + OFF_DN;
    float* SP    = ws + OFF_SP;
    float* SN    = ws + OFF_SN;
    float* offsP = ws + OFF_OFFSP;
    float* offsN = ws + OFF_OFFSN;
    float* SNtot = ws + OFF_SNTOT;

    k0_transpose<<<dim3(FO), dim3(FIN), 0, stream>>>(W, Wt);
    k1_gemm<<<dim3(B_ * N_ / 64), dim3(128), 0, stream>>>(h, Wt, a, Wh, s1, s2);
    k2_sort<<<dim3(B_), dim3(1024), 0, stream>>>(s2, ssort, sord, e2p, e2n, DP, DN);
    k3_scan<<<dim3(B_ * NCHUNK), dim3(128), 0, stream>>>(Wh, sord, e2p, e2n, SP, SN);
    k3b_offs<<<dim3(B_), dim3(128), 0, stream>>>(SP, SN, offsP, offsN, SNtot);
    k4_final<<<dim3(B_ * N_ / 2), dim3(256), 0, stream>>>(s1, ssort, DP, DN, SP, SN,
                                                          offsP, offsN, SNtot, out);
}

// Round 2
// 93.221 us; speedup vs baseline: 1.3385x; 1.3385x over previous
//
#include <hip/hip_runtime.h>
#include <math.h>
#include <stdint.h>

#define B_    8
#define N_    2048
#define FIN   256
#define FO    128
#define ALPHA 0.2f
#define NCHUNK 64
#define CHUNK  32   // N_/NCHUNK

// ---------------- workspace layout (float elements) ----------------
static const size_t OFF_WH    = 0;
static const size_t OFF_WT    = OFF_WH    + (size_t)B_*N_*FO;
static const size_t OFF_S1    = OFF_WT    + (size_t)FO*FIN;
static const size_t OFF_S2    = OFF_S1    + (size_t)B_*N_;
static const size_t OFF_SSORT = OFF_S2    + (size_t)B_*N_;
static const size_t OFF_SORD  = OFF_SSORT + (size_t)B_*N_;
static const size_t OFF_E2P   = OFF_SORD  + (size_t)B_*N_;
static const size_t OFF_E2N   = OFF_E2P   + (size_t)B_*N_;
static const size_t OFF_DP    = OFF_E2N   + (size_t)B_*N_;
static const size_t OFF_DN    = OFF_DP    + (size_t)B_*N_;
static const size_t OFF_KCUT  = OFF_DN    + (size_t)B_*N_;
static const size_t OFF_SP    = OFF_KCUT  + (size_t)B_*N_;
static const size_t OFF_SN    = OFF_SP    + (size_t)B_*N_*FO;
static const size_t OFF_OFFSP = OFF_SN    + (size_t)B_*N_*FO;
static const size_t OFF_OFFSN = OFF_OFFSP + (size_t)B_*NCHUNK*FO;
static const size_t OFF_SNTOT = OFF_OFFSN + (size_t)B_*NCHUNK*FO;

// ---------------- K0: transpose W -> Wt[f][k] ----------------
__global__ void k0_transpose(const float* __restrict__ W, float* __restrict__ Wt) {
    int f = blockIdx.x;    // 0..127
    int k = threadIdx.x;   // 0..255
    Wt[f * FIN + k] = W[k * FO + f];
}

// ---------------- K1: Wh = h @ W  (+ fused s1, s2) ----------------
__global__ __launch_bounds__(128) void k1_gemm(const float* __restrict__ h,
                                               const float* __restrict__ Wt,
                                               const float* __restrict__ a,
                                               float* __restrict__ Wh,
                                               float* __restrict__ s1g,
                                               float* __restrict__ s2g) {
    __shared__ __align__(16) float hS[64 * 36];    // [i][k] stride 36
    __shared__ __align__(16) float wS[128 * 36];   // [f][k] stride 36
    __shared__ float red1[64][16];
    __shared__ float red2[64][16];

    const int tid = threadIdx.x;
    const int fg  = tid & 15;   // 16 f-groups, f = fg + 16c
    const int ig  = tid >> 4;   // 8 i-groups,  i = ig + 8r
    const int row0 = blockIdx.x * 64;

    float acc[8][8];
#pragma unroll
    for (int r = 0; r < 8; ++r)
#pragma unroll
        for (int c = 0; c < 8; ++c) acc[r][c] = 0.f;

    for (int kt = 0; kt < FIN; kt += 32) {
#pragma unroll
        for (int p = 0; p < 4; ++p) {
            int idx = p * 128 + tid;
            int ri = idx >> 3, c4 = (idx & 7) * 4;
            *(float4*)&hS[ri * 36 + c4] =
                *(const float4*)&h[(size_t)(row0 + ri) * FIN + kt + c4];
        }
#pragma unroll
        for (int p = 0; p < 8; ++p) {
            int idx = p * 128 + tid;
            int f = idx >> 3, c4 = (idx & 7) * 4;
            *(float4*)&wS[f * 36 + c4] =
                *(const float4*)&Wt[f * FIN + kt + c4];
        }
        __syncthreads();

        for (int kk = 0; kk < 32; kk += 4) {
            float4 hf[8], wf[8];
#pragma unroll
            for (int r = 0; r < 8; ++r) hf[r] = *(float4*)&hS[(ig + 8 * r) * 36 + kk];
#pragma unroll
            for (int c = 0; c < 8; ++c) wf[c] = *(float4*)&wS[(fg + 16 * c) * 36 + kk];
#pragma unroll
            for (int r = 0; r < 8; ++r)
#pragma unroll
                for (int c = 0; c < 8; ++c) {
                    acc[r][c] += hf[r].x * wf[c].x;
                    acc[r][c] += hf[r].y * wf[c].y;
                    acc[r][c] += hf[r].z * wf[c].z;
                    acc[r][c] += hf[r].w * wf[c].w;
                }
        }
        __syncthreads();
    }

#pragma unroll
    for (int r = 0; r < 8; ++r)
#pragma unroll
        for (int c = 0; c < 8; ++c)
            Wh[(size_t)(row0 + ig + 8 * r) * FO + fg + 16 * c] = acc[r][c];

    float a1v[8], a2v[8];
#pragma unroll
    for (int c = 0; c < 8; ++c) {
        a1v[c] = a[fg + 16 * c];
        a2v[c] = a[FO + fg + 16 * c];
    }
#pragma unroll
    for (int r = 0; r < 8; ++r) {
        float p1 = 0.f, p2 = 0.f;
#pragma unroll
        for (int c = 0; c < 8; ++c) {
            p1 += acc[r][c] * a1v[c];
            p2 += acc[r][c] * a2v[c];
        }
        red1[ig + 8 * r][fg] = p1;
        red2[ig + 8 * r][fg] = p2;
    }
    __syncthreads();
    if (tid < 128) {
        int li = tid & 63, which = tid >> 6;
        float s = 0.f;
        if (which == 0) {
#pragma unroll
            for (int g = 0; g < 16; ++g) s += red1[li][g];
            s1g[row0 + li] = s;
        } else {
#pragma unroll
            for (int g = 0; g < 16; ++g) s += red2[li][g];
            s2g[row0 + li] = s;
        }
    }
}

// ---------------- K2a: brute-force rank + scatter (replaces bitonic sort) ----------------
// grid = B_*16 blocks, 512 threads. Each block ranks 128 elements of one batch;
// 4 threads per element, each scanning a 512-element quarter of the key array.
__global__ __launch_bounds__(512) void k2a_rank(const float* __restrict__ s2g,
                                                float* __restrict__ ssort,
                                                int* __restrict__ sord) {
    __shared__ uint64_t keys[N_];   // 16 KB
    __shared__ int part[512];
    const int b = blockIdx.x >> 4, c = blockIdx.x & 15;
    const int tid = threadIdx.x;

    for (int t = tid; t < N_; t += 512) {
        unsigned u = __float_as_uint(s2g[b * N_ + t]);
        u = (u & 0x80000000u) ? ~u : (u | 0x80000000u);   // order-preserving map
        keys[t] = ((uint64_t)u << 16) | (unsigned)t;      // unique keys -> no ties
    }
    __syncthreads();

    const int le = tid & 127;        // local element 0..127
    const int e  = c * 128 + le;     // element index in batch
    const int q  = tid >> 7;         // quarter 0..3
    const uint64_t myk = keys[e];
    const uint64_t* kp = keys + q * 512;
    int cnt = 0;
#pragma unroll 8
    for (int kk = 0; kk < 512; ++kk) cnt += (int)(kp[kk] > myk);   // rank among desc order
    part[tid] = cnt;
    __syncthreads();

    if (tid < 128) {
        int rank = part[tid] + part[tid + 128] + part[tid + 256] + part[tid + 384];
        ssort[b * N_ + rank] = s2g[b * N_ + e];
        sord[b * N_ + rank]  = e;
    }
}

// ---------------- K2b: exps + scalar prefix scans + per-row cutoff search ----------------
// one block per batch, 256 threads, each owns 8 consecutive sorted positions
__global__ __launch_bounds__(256) void k2b_scan(const float* __restrict__ ssort,
                                                const float* __restrict__ s1g,
                                                float* __restrict__ e2p,
                                                float* __restrict__ e2n,
                                                float* __restrict__ DP,
                                                float* __restrict__ DN,
                                                int* __restrict__ kcut) {
    __shared__ float sv[N_];          // sorted values, for binary searches
    __shared__ float tp[256], tn[256];
    const int b = blockIdx.x, tid = threadIdx.x;
    const size_t base = (size_t)b * N_;

    float v[8], lp[8], ln[8];
    *(float4*)&v[0] = *(const float4*)&ssort[base + tid * 8];
    *(float4*)&v[4] = *(const float4*)&ssort[base + tid * 8 + 4];
    float ap = 0.f, an = 0.f;
    float pv[8], nv[8];
#pragma unroll
    for (int j = 0; j < 8; ++j) {
        sv[tid * 8 + j] = v[j];
        float p = expf(v[j]), n = expf(ALPHA * v[j]);
        pv[j] = p; nv[j] = n;
        ap += p; lp[j] = ap;
        an += n; ln[j] = an;
    }
    *(float4*)&e2p[base + tid * 8]     = *(float4*)&pv[0];
    *(float4*)&e2p[base + tid * 8 + 4] = *(float4*)&pv[4];
    *(float4*)&e2n[base + tid * 8]     = *(float4*)&nv[0];
    *(float4*)&e2n[base + tid * 8 + 4] = *(float4*)&nv[4];
    tp[tid] = ap; tn[tid] = an;
    __syncthreads();

    // Hillis-Steele over the 256 per-thread totals
    for (int off = 1; off < 256; off <<= 1) {
        float xp = tp[tid], xn = tn[tid];
        if (tid >= off) { xp += tp[tid - off]; xn += tn[tid - off]; }
        __syncthreads();
        tp[tid] = xp; tn[tid] = xn;
        __syncthreads();
    }
    float offp = (tid > 0) ? tp[tid - 1] : 0.f;
    float offn = (tid > 0) ? tn[tid - 1] : 0.f;
    float dpv[8], dnv[8];
#pragma unroll
    for (int j = 0; j < 8; ++j) { dpv[j] = lp[j] + offp; dnv[j] = ln[j] + offn; }
    *(float4*)&DP[base + tid * 8]     = *(float4*)&dpv[0];
    *(float4*)&DP[base + tid * 8 + 4] = *(float4*)&dpv[4];
    *(float4*)&DN[base + tid * 8]     = *(float4*)&dnv[0];
    *(float4*)&DN[base + tid * 8 + 4] = *(float4*)&dnv[4];

    // per-row cutoff: k = #{ sorted >= -s1[row] }  (sv already complete)
#pragma unroll
    for (int r = 0; r < 8; ++r) {
        int row = tid + 256 * r;
        float target = -s1g[base + row];
        int lo = 0, hi = N_;
        while (lo < hi) {
            int mid = (lo + hi) >> 1;
            if (sv[mid] >= target) lo = mid + 1; else hi = mid;
        }
        kcut[base + row] = lo;
    }
}

// ---------------- K3: chunk-local vector prefix scans ----------------
// grid = B_*NCHUNK (=512) blocks, 128 threads (one per f)
__global__ __launch_bounds__(128) void k3_scan(const float* __restrict__ Wh,
                                               const int* __restrict__ sord,
                                               const float* __restrict__ e2p,
                                               const float* __restrict__ e2n,
                                               float* __restrict__ SP,
                                               float* __restrict__ SN) {
    const int b = blockIdx.x >> 6, ch = blockIdx.x & 63;
    const int f = threadIdx.x;
    const size_t base = (size_t)b * N_;
    const int k0 = ch * CHUNK;
    float accP = 0.f, accN = 0.f;

    int ord = sord[base + k0];
    float x = Wh[(base + ord) * FO + f];
#pragma unroll 4
    for (int k = k0; k < k0 + CHUNK; ++k) {
        float xc = x;
        float wp = e2p[base + k];
        float wn = e2n[base + k];
        if (k + 1 < k0 + CHUNK) {
            int ordn = sord[base + k + 1];
            x = Wh[(base + ordn) * FO + f];
        }
        accP += wp * xc;
        accN += wn * xc;
        SP[(base + k) * FO + f] = accP;
        SN[(base + k) * FO + f] = accN;
    }
}

// ---------------- K3b: per-batch chunk-offset scan in LDS ----------------
// 8 blocks, 256 threads
__global__ __launch_bounds__(256) void k3b_offs(const float* __restrict__ SP,
                                                const float* __restrict__ SN,
                                                float* __restrict__ offsP,
                                                float* __restrict__ offsN,
                                                float* __restrict__ SNtot) {
    __shared__ float ctP[NCHUNK][FO];   // 32 KB
    __shared__ float ctN[NCHUNK][FO];   // 32 KB
    __shared__ float halfTotP[2][FO], halfTotN[2][FO];
    const int b = blockIdx.x, tid = threadIdx.x;
    const size_t base = (size_t)b * N_;

    for (int idx = tid; idx < NCHUNK * FO; idx += 256) {
        int c = idx >> 7, f = idx & 127;
        ctP[c][f] = SP[(base + c * CHUNK + CHUNK - 1) * FO + f];
        ctN[c][f] = SN[(base + c * CHUNK + CHUNK - 1) * FO + f];
    }
    __syncthreads();

    const int f = tid & 127, hh = tid >> 7;
    float rp = 0.f, rn = 0.f;
    for (int c = hh * 32; c < hh * 32 + 32; ++c) {
        float tpv = ctP[c][f], tnv = ctN[c][f];
        ctP[c][f] = rp; ctN[c][f] = rn;     // exclusive, local to half
        rp += tpv; rn += tnv;
    }
    halfTotP[hh][f] = rp; halfTotN[hh][f] = rn;
    __syncthreads();

    float addP = hh ? halfTotP[0][f] : 0.f;
    float addN = hh ? halfTotN[0][f] : 0.f;
    for (int c = hh * 32; c < hh * 32 + 32; ++c) {
        offsP[((size_t)b * NCHUNK + c) * FO + f] = ctP[c][f] + addP;
        offsN[((size_t)b * NCHUNK + c) * FO + f] = ctN[c][f] + addN;
    }
    if (tid < FO) SNtot[b * FO + tid] = halfTotN[0][tid] + halfTotN[1][tid];
}

// ---------------- K4: combine + elu (cutoffs precomputed) ----------------
// grid = B_*N_/2 blocks, 256 threads (2 rows x 128 f)
__global__ __launch_bounds__(256) void k4_final(const float* __restrict__ s1g,
                                                const int* __restrict__ kcut,
                                                const float* __restrict__ DP,
                                                const float* __restrict__ DN,
                                                const float* __restrict__ SP,
                                                const float* __restrict__ SN,
                                                const float* __restrict__ offsP,
                                                const float* __restrict__ offsN,
                                                const float* __restrict__ SNtot,
                                                float* __restrict__ out) {
    const int rowg = blockIdx.x * 2 + (threadIdx.x >> 7);
    const int f = threadIdx.x & 127;
    const int b = rowg >> 11;
    const size_t base = (size_t)b * N_;

    const float s1v = s1g[rowg];
    const int k = kcut[rowg];

    const float ep1 = expf(s1v), en1 = expf(ALPHA * s1v);
    float dp = 0.f, dn = 0.f, sp = 0.f, sn = 0.f;
    if (k > 0) {
        dp = DP[base + k - 1];
        dn = DN[base + k - 1];
        int c = (k - 1) / CHUNK;
        size_t ro = (base + k - 1) * FO + f;
        sp = offsP[((size_t)b * NCHUNK + c) * FO + f] + SP[ro];
        sn = offsN[((size_t)b * NCHUNK + c) * FO + f] + SN[ro];
    }
    const float dnt = DN[base + N_ - 1];
    const float snt = SNtot[b * FO + f];

    const float den = ep1 * dp + en1 * (dnt - dn);
    const float num = ep1 * sp + en1 * (snt - sn);
    const float o = num / den;
    out[(size_t)rowg * FO + f] = (o > 0.f) ? o : (expf(o) - 1.f);
}

// ---------------- launch ----------------
extern "C" void kernel_launch(void* const* d_in, const int* in_sizes, int n_in,
                              void* d_out, int out_size, void* d_ws, size_t ws_size,
                              hipStream_t stream) {
    const float* h = (const float*)d_in[0];
    const float* W = (const float*)d_in[1];
    const float* a = (const float*)d_in[2];
    float* out = (float*)d_out;
    float* ws = (float*)d_ws;

    float* Wh    = ws + OFF_WH;
    float* Wt    = ws + OFF_WT;
    float* s1    = ws + OFF_S1;
    float* s2    = ws + OFF_S2;
    float* ssort = ws + OFF_SSORT;
    int*   sord  = (int*)(ws + OFF_SORD);
    float* e2p   = ws + OFF_E2P;
    float* e2n   = ws + OFF_E2N;
    float* DP    = ws + OFF_DP;
    float* DN    = ws + OFF_DN;
    int*   kcut  = (int*)(ws + OFF_KCUT);
    float* SP    = ws + OFF_SP;
    float* SN    = ws + OFF_SN;
    float* offsP = ws + OFF_OFFSP;
    float* offsN = ws + OFF_OFFSN;
    float* SNtot = ws + OFF_SNTOT;

    k0_transpose<<<dim3(FO), dim3(FIN), 0, stream>>>(W, Wt);
    k1_gemm<<<dim3(B_ * N_ / 64), dim3(128), 0, stream>>>(h, Wt, a, Wh, s1, s2);
    k2a_rank<<<dim3(B_ * 16), dim3(512), 0, stream>>>(s2, ssort, sord);
    k2b_scan<<<dim3(B_), dim3(256), 0, stream>>>(ssort, s1, e2p, e2n, DP, DN, kcut);
    k3_scan<<<dim3(B_ * NCHUNK), dim3(128), 0, stream>>>(Wh, sord, e2p, e2n, SP, SN);
    k3b_offs<<<dim3(B_), dim3(256), 0, stream>>>(SP, SN, offsP, offsN, SNtot);
    k4_final<<<dim3(B_ * N_ / 2), dim3(256), 0, stream>>>(s1, kcut, DP, DN, SP, SN,
                                                          offsP, offsN, SNtot, out);
}

// Round 3
// 86.609 us; speedup vs baseline: 1.4407x; 1.0763x over previous
//
#include <hip/hip_runtime.h>
#include <math.h>
#include <stdint.h>

#define B_    8
#define N_    2048
#define FIN   256
#define FO    128
#define ALPHA 0.2f
#define NCHUNK 64
#define CHUNK  32   // N_/NCHUNK

// ---------------- workspace layout (float elements) ----------------
static const size_t OFF_WH    = 0;                                   // B*N*FO
static const size_t OFF_S1    = OFF_WH    + (size_t)B_*N_*FO;
static const size_t OFF_S2    = OFF_S1    + (size_t)B_*N_;
static const size_t OFF_SSORT = OFF_S2    + (size_t)B_*N_;
static const size_t OFF_SORD  = OFF_SSORT + (size_t)B_*N_;
static const size_t OFF_E2P   = OFF_SORD  + (size_t)B_*N_;
static const size_t OFF_E2N   = OFF_E2P   + (size_t)B_*N_;
static const size_t OFF_DPN   = OFF_E2N   + (size_t)B_*N_;           // float2 * B*N
static const size_t OFF_KCUT  = OFF_DPN   + (size_t)2*B_*N_;
static const size_t OFF_SPN   = OFF_KCUT  + (size_t)B_*N_;           // float2 * B*N*FO
static const size_t OFF_OFFS  = OFF_SPN   + (size_t)2*B_*N_*FO;      // float2 * B*NCHUNK*FO
static const size_t OFF_SNTOT = OFF_OFFS  + (size_t)2*B_*NCHUNK*FO;

// ---------------- K1: Wh = h @ W  (+ fused s1, s2), W transposed in-LDS ----------------
// 256 blocks (64 rows each), 128 threads, 8x8 register tile, reg double-buffered staging.
__global__ __launch_bounds__(128, 1) void k1_gemm(const float* __restrict__ h,
                                                  const float* __restrict__ W,
                                                  const float* __restrict__ a,
                                                  float* __restrict__ Wh,
                                                  float* __restrict__ s1g,
                                                  float* __restrict__ s2g) {
    __shared__ __align__(16) float hS[64 * 36];    // [i][k] stride 36
    __shared__ __align__(16) float wS[128 * 36];   // [f][k] stride 36
    __shared__ float red1[64][16];
    __shared__ float red2[64][16];

    const int tid = threadIdx.x;
    const int fg  = tid & 15;   // 16 f-groups, f = fg + 16c
    const int ig  = tid >> 4;   // 8 i-groups,  i = ig + 8r
    const int row0 = blockIdx.x * 64;

    float acc[8][8];
#pragma unroll
    for (int r = 0; r < 8; ++r)
#pragma unroll
        for (int c = 0; c < 8; ++c) acc[r][c] = 0.f;

    // staging registers
    float4 hreg[4];
    float  wreg[8][4];

    // h-tile addresses: idx = p*128+tid; row = idx>>3, col4 = (idx&7)*4
    // W-tile: idx = p*128+tid; k_local = idx>>5 (0..31), f = (idx&31) + 32*j (j=0..3)
    const int h_ri = tid >> 3, h_c4 = (tid & 7) * 4;           // with p folded below
    const int w_kl_base = tid >> 5, w_f0 = tid & 31;

    // prefetch kt = 0
#pragma unroll
    for (int p = 0; p < 4; ++p) {
        int ri = (p * 128 + tid) >> 3, c4 = ((p * 128 + tid) & 7) * 4;
        hreg[p] = *(const float4*)&h[(size_t)(row0 + ri) * FIN + 0 + c4];
    }
#pragma unroll
    for (int p = 0; p < 8; ++p) {
        int kl = (p * 128 + tid) >> 5, f0 = (p * 128 + tid) & 31;
#pragma unroll
        for (int j = 0; j < 4; ++j)
            wreg[p][j] = W[(size_t)(0 + kl) * FO + f0 + 32 * j];
    }
    (void)h_ri; (void)h_c4; (void)w_kl_base; (void)w_f0;

    for (int kt = 0; kt < FIN; kt += 32) {
        // store staged registers to LDS
#pragma unroll
        for (int p = 0; p < 4; ++p) {
            int ri = (p * 128 + tid) >> 3, c4 = ((p * 128 + tid) & 7) * 4;
            *(float4*)&hS[ri * 36 + c4] = hreg[p];
        }
#pragma unroll
        for (int p = 0; p < 8; ++p) {
            int kl = (p * 128 + tid) >> 5, f0 = (p * 128 + tid) & 31;
#pragma unroll
            for (int j = 0; j < 4; ++j)
                wS[(f0 + 32 * j) * 36 + kl] = wreg[p][j];
        }
        __syncthreads();

        // issue next tile's global loads (in flight during compute)
        if (kt + 32 < FIN) {
#pragma unroll
            for (int p = 0; p < 4; ++p) {
                int ri = (p * 128 + tid) >> 3, c4 = ((p * 128 + tid) & 7) * 4;
                hreg[p] = *(const float4*)&h[(size_t)(row0 + ri) * FIN + kt + 32 + c4];
            }
#pragma unroll
            for (int p = 0; p < 8; ++p) {
                int kl = (p * 128 + tid) >> 5, f0 = (p * 128 + tid) & 31;
#pragma unroll
                for (int j = 0; j < 4; ++j)
                    wreg[p][j] = W[(size_t)(kt + 32 + kl) * FO + f0 + 32 * j];
            }
        }

        for (int kk = 0; kk < 32; kk += 4) {
            float4 hf[8], wf[8];
#pragma unroll
            for (int r = 0; r < 8; ++r) hf[r] = *(float4*)&hS[(ig + 8 * r) * 36 + kk];
#pragma unroll
            for (int c = 0; c < 8; ++c) wf[c] = *(float4*)&wS[(fg + 16 * c) * 36 + kk];
#pragma unroll
            for (int r = 0; r < 8; ++r)
#pragma unroll
                for (int c = 0; c < 8; ++c) {
                    acc[r][c] += hf[r].x * wf[c].x;
                    acc[r][c] += hf[r].y * wf[c].y;
                    acc[r][c] += hf[r].z * wf[c].z;
                    acc[r][c] += hf[r].w * wf[c].w;
                }
        }
        __syncthreads();
    }

#pragma unroll
    for (int r = 0; r < 8; ++r)
#pragma unroll
        for (int c = 0; c < 8; ++c)
            Wh[(size_t)(row0 + ig + 8 * r) * FO + fg + 16 * c] = acc[r][c];

    float a1v[8], a2v[8];
#pragma unroll
    for (int c = 0; c < 8; ++c) {
        a1v[c] = a[fg + 16 * c];
        a2v[c] = a[FO + fg + 16 * c];
    }
#pragma unroll
    for (int r = 0; r < 8; ++r) {
        float p1 = 0.f, p2 = 0.f;
#pragma unroll
        for (int c = 0; c < 8; ++c) {
            p1 += acc[r][c] * a1v[c];
            p2 += acc[r][c] * a2v[c];
        }
        red1[ig + 8 * r][fg] = p1;
        red2[ig + 8 * r][fg] = p2;
    }
    __syncthreads();
    if (tid < 128) {
        int li = tid & 63, which = tid >> 6;
        float s = 0.f;
        if (which == 0) {
#pragma unroll
            for (int g = 0; g < 16; ++g) s += red1[li][g];
            s1g[row0 + li] = s;
        } else {
#pragma unroll
            for (int g = 0; g < 16; ++g) s += red2[li][g];
            s2g[row0 + li] = s;
        }
    }
}

// ---------------- K2a: brute-force rank + scatter ----------------
__global__ __launch_bounds__(512) void k2a_rank(const float* __restrict__ s2g,
                                                float* __restrict__ ssort,
                                                int* __restrict__ sord) {
    __shared__ uint64_t keys[N_];   // 16 KB
    __shared__ int part[512];
    const int b = blockIdx.x >> 4, c = blockIdx.x & 15;
    const int tid = threadIdx.x;

    for (int t = tid; t < N_; t += 512) {
        unsigned u = __float_as_uint(s2g[b * N_ + t]);
        u = (u & 0x80000000u) ? ~u : (u | 0x80000000u);   // order-preserving map
        keys[t] = ((uint64_t)u << 16) | (unsigned)t;      // unique keys -> no ties
    }
    __syncthreads();

    const int le = tid & 127;
    const int e  = c * 128 + le;
    const int q  = tid >> 7;
    const uint64_t myk = keys[e];
    const uint64_t* kp = keys + q * 512;
    int cnt = 0;
#pragma unroll 8
    for (int kk = 0; kk < 512; ++kk) cnt += (int)(kp[kk] > myk);
    part[tid] = cnt;
    __syncthreads();

    if (tid < 128) {
        int rank = part[tid] + part[tid + 128] + part[tid + 256] + part[tid + 384];
        ssort[b * N_ + rank] = s2g[b * N_ + e];
        sord[b * N_ + rank]  = e;
    }
}

// ---------------- K2b: exps + scalar scans + per-row cutoff (ILP searches) ----------------
__global__ __launch_bounds__(256) void k2b_scan(const float* __restrict__ ssort,
                                                const float* __restrict__ s1g,
                                                float* __restrict__ e2p,
                                                float* __restrict__ e2n,
                                                float2* __restrict__ DPN,
                                                int* __restrict__ kcut) {
    __shared__ float sv[N_];
    __shared__ float tp[256], tn[256];
    const int b = blockIdx.x, tid = threadIdx.x;
    const size_t base = (size_t)b * N_;

    float v[8], lp[8], ln[8];
    *(float4*)&v[0] = *(const float4*)&ssort[base + tid * 8];
    *(float4*)&v[4] = *(const float4*)&ssort[base + tid * 8 + 4];
    float ap = 0.f, an = 0.f;
    float pv[8], nv[8];
#pragma unroll
    for (int j = 0; j < 8; ++j) {
        sv[tid * 8 + j] = v[j];
        float p = expf(v[j]), n = expf(ALPHA * v[j]);
        pv[j] = p; nv[j] = n;
        ap += p; lp[j] = ap;
        an += n; ln[j] = an;
    }
    *(float4*)&e2p[base + tid * 8]     = *(float4*)&pv[0];
    *(float4*)&e2p[base + tid * 8 + 4] = *(float4*)&pv[4];
    *(float4*)&e2n[base + tid * 8]     = *(float4*)&nv[0];
    *(float4*)&e2n[base + tid * 8 + 4] = *(float4*)&nv[4];
    tp[tid] = ap; tn[tid] = an;
    __syncthreads();

    for (int off = 1; off < 256; off <<= 1) {
        float xp = tp[tid], xn = tn[tid];
        if (tid >= off) { xp += tp[tid - off]; xn += tn[tid - off]; }
        __syncthreads();
        tp[tid] = xp; tn[tid] = xn;
        __syncthreads();
    }
    float offp = (tid > 0) ? tp[tid - 1] : 0.f;
    float offn = (tid > 0) ? tn[tid - 1] : 0.f;
#pragma unroll
    for (int j = 0; j < 8; ++j) {
        DPN[base + tid * 8 + j] = make_float2(lp[j] + offp, ln[j] + offn);
    }

    // per-row cutoffs: 8 interleaved fixed-step binary searches (ILP)
    float tgt[8];
    int lo[8], hi[8];
#pragma unroll
    for (int r = 0; r < 8; ++r) {
        tgt[r] = -s1g[base + tid + 256 * r];
        lo[r] = 0; hi[r] = N_;
    }
#pragma unroll
    for (int step = 0; step < 12; ++step) {
#pragma unroll
        for (int r = 0; r < 8; ++r) {
            int mid = (lo[r] + hi[r]) >> 1;
            bool live = lo[r] < hi[r];
            float pv2 = sv[mid & (N_ - 1)];
            bool c = live && (pv2 >= tgt[r]);
            lo[r] = c ? mid + 1 : lo[r];
            hi[r] = (live && !c) ? mid : hi[r];
        }
    }
#pragma unroll
    for (int r = 0; r < 8; ++r) kcut[base + tid + 256 * r] = lo[r];
}

// ---------------- K3: chunk-local vector prefix scans (float2 out, 4-deep pipeline) ----------------
// grid = B_*NCHUNK (=512) blocks, 128 threads (one per f)
__global__ __launch_bounds__(128) void k3_scan(const float* __restrict__ Wh,
                                               const int* __restrict__ sord,
                                               const float* __restrict__ e2p,
                                               const float* __restrict__ e2n,
                                               float2* __restrict__ SPN) {
    const int b = blockIdx.x >> 6, ch = blockIdx.x & 63;
    const int f = threadIdx.x;
    const size_t base = (size_t)b * N_;
    const int k0 = ch * CHUNK;
    float accP = 0.f, accN = 0.f;

    float cur[4];
#pragma unroll
    for (int j = 0; j < 4; ++j)
        cur[j] = Wh[(base + sord[base + k0 + j]) * FO + f];

    for (int kb = k0; kb < k0 + CHUNK; kb += 4) {
        float nxt[4];
        if (kb + 4 < k0 + CHUNK) {
#pragma unroll
            for (int j = 0; j < 4; ++j)
                nxt[j] = Wh[(base + sord[base + kb + 4 + j]) * FO + f];
        }
#pragma unroll
        for (int j = 0; j < 4; ++j) {
            accP += e2p[base + kb + j] * cur[j];
            accN += e2n[base + kb + j] * cur[j];
            SPN[(base + kb + j) * FO + f] = make_float2(accP, accN);
        }
#pragma unroll
        for (int j = 0; j < 4; ++j) cur[j] = nxt[j];
    }
}

// ---------------- K3b: per-batch chunk-offset scan in LDS (float2) ----------------
// 8 blocks, 256 threads
__global__ __launch_bounds__(256) void k3b_offs(const float2* __restrict__ SPN,
                                                float2* __restrict__ OFFS,
                                                float* __restrict__ SNtot) {
    __shared__ float2 ct[NCHUNK][FO];            // 64 KB
    __shared__ float2 halfTot[2][FO];
    const int b = blockIdx.x, tid = threadIdx.x;
    const size_t base = (size_t)b * N_;

    for (int idx = tid; idx < NCHUNK * FO; idx += 256) {
        int c = idx >> 7, f = idx & 127;
        ct[c][f] = SPN[(base + c * CHUNK + CHUNK - 1) * FO + f];
    }
    __syncthreads();

    const int f = tid & 127, hh = tid >> 7;
    float rp = 0.f, rn = 0.f;
    for (int c = hh * 32; c < hh * 32 + 32; ++c) {
        float2 t = ct[c][f];
        ct[c][f] = make_float2(rp, rn);          // exclusive, local to half
        rp += t.x; rn += t.y;
    }
    halfTot[hh][f] = make_float2(rp, rn);
    __syncthreads();

    float addP = hh ? halfTot[0][f].x : 0.f;
    float addN = hh ? halfTot[0][f].y : 0.f;
    for (int c = hh * 32; c < hh * 32 + 32; ++c) {
        float2 t = ct[c][f];
        OFFS[((size_t)b * NCHUNK + c) * FO + f] = make_float2(t.x + addP, t.y + addN);
    }
    if (tid < FO) SNtot[b * FO + tid] = halfTot[0][tid].y + halfTot[1][tid].y;
}

// ---------------- K4: combine + elu ----------------
// grid = B_*N_/2 blocks, 256 threads (2 rows x 128 f)
__global__ __launch_bounds__(256) void k4_final(const float* __restrict__ s1g,
                                                const int* __restrict__ kcut,
                                                const float2* __restrict__ DPN,
                                                const float2* __restrict__ SPN,
                                                const float2* __restrict__ OFFS,
                                                const float* __restrict__ SNtot,
                                                float* __restrict__ out) {
    const int rowg = blockIdx.x * 2 + (threadIdx.x >> 7);
    const int f = threadIdx.x & 127;
    const int b = rowg >> 11;
    const size_t base = (size_t)b * N_;

    const float s1v = s1g[rowg];
    const int k = kcut[rowg];

    const float ep1 = expf(s1v), en1 = expf(ALPHA * s1v);
    float dp = 0.f, dn = 0.f, sp = 0.f, sn = 0.f;
    if (k > 0) {
        float2 d = DPN[base + k - 1];
        dp = d.x; dn = d.y;
        int c = (k - 1) >> 5;   // CHUNK=32
        float2 s = SPN[(base + k - 1) * FO + f];
        float2 o = OFFS[((size_t)b * NCHUNK + c) * FO + f];
        sp = o.x + s.x;
        sn = o.y + s.y;
    }
    const float dnt = DPN[base + N_ - 1].y;
    const float snt = SNtot[b * FO + f];

    const float den = ep1 * dp + en1 * (dnt - dn);
    const float num = ep1 * sp + en1 * (snt - sn);
    const float o = num / den;
    out[(size_t)rowg * FO + f] = (o > 0.f) ? o : (expf(o) - 1.f);
}

// ---------------- launch ----------------
extern "C" void kernel_launch(void* const* d_in, const int* in_sizes, int n_in,
                              void* d_out, int out_size, void* d_ws, size_t ws_size,
                              hipStream_t stream) {
    const float* h = (const float*)d_in[0];
    const float* W = (const float*)d_in[1];
    const float* a = (const float*)d_in[2];
    float* out = (float*)d_out;
    float* ws = (float*)d_ws;

    float*  Wh    = ws + OFF_WH;
    float*  s1    = ws + OFF_S1;
    float*  s2    = ws + OFF_S2;
    float*  ssort = ws + OFF_SSORT;
    int*    sord  = (int*)(ws + OFF_SORD);
    float*  e2p   = ws + OFF_E2P;
    float*  e2n   = ws + OFF_E2N;
    float2* DPN   = (float2*)(ws + OFF_DPN);
    int*    kcut  = (int*)(ws + OFF_KCUT);
    float2* SPN   = (float2*)(ws + OFF_SPN);
    float2* OFFS  = (float2*)(ws + OFF_OFFS);
    float*  SNtot = ws + OFF_SNTOT;

    k1_gemm<<<dim3(B_ * N_ / 64), dim3(128), 0, stream>>>(h, W, a, Wh, s1, s2);
    k2a_rank<<<dim3(B_ * 16), dim3(512), 0, stream>>>(s2, ssort, sord);
    k2b_scan<<<dim3(B_), dim3(256), 0, stream>>>(ssort, s1, e2p, e2n, DPN, kcut);
    k3_scan<<<dim3(B_ * NCHUNK), dim3(128), 0, stream>>>(Wh, sord, e2p, e2n, SPN);
    k3b_offs<<<dim3(B_), dim3(256), 0, stream>>>(SPN, OFFS, SNtot);
    k4_final<<<dim3(B_ * N_ / 2), dim3(256), 0, stream>>>(s1, kcut, DPN, SPN,
                                                          OFFS, SNtot, out);
}

// Round 4
// 74.993 us; speedup vs baseline: 1.6639x; 1.1549x over previous
//
#include <hip/hip_runtime.h>
#include <math.h>
#include <stdint.h>

#define B_    8
#define N_    2048
#define FIN   256
#define FO    128
#define ALPHA 0.2f
#define NCHUNK 64
#define CHUNK  32   // N_/NCHUNK

// ---------------- workspace layout (float elements) ----------------
static const size_t OFF_WH    = 0;                                   // B*N*FO
static const size_t OFF_S1    = OFF_WH    + (size_t)B_*N_*FO;
static const size_t OFF_S2    = OFF_S1    + (size_t)B_*N_;
static const size_t OFF_SSORT = OFF_S2    + (size_t)B_*N_;
static const size_t OFF_SORD  = OFF_SSORT + (size_t)B_*N_;
static const size_t OFF_E2P   = OFF_SORD  + (size_t)B_*N_;
static const size_t OFF_E2N   = OFF_E2P   + (size_t)B_*N_;
static const size_t OFF_DPN   = OFF_E2N   + (size_t)B_*N_;           // float2 * B*N
static const size_t OFF_KCUT  = OFF_DPN   + (size_t)2*B_*N_;
static const size_t OFF_SPN   = OFF_KCUT  + (size_t)B_*N_;           // float2 * B*N*FO
static const size_t OFF_OFFS  = OFF_SPN   + (size_t)2*B_*N_*FO;      // float2 * B*NCHUNK*FO
static const size_t OFF_SNTOT = OFF_OFFS  + (size_t)2*B_*NCHUNK*FO;
static const size_t OFF_CT    = OFF_SNTOT + (size_t)B_*FO;           // float2 * B*NCHUNK*FO

// ---------------- K1: Wh = h @ W (+ fused s1,s2) ----------------
// grid 256 blocks (BM=64 rows), 256 threads, 8m x 4n per thread, K-step 32.
// hS transposed [k][m] so compute-reads broadcast; wS [k][n] conflict-free.
__global__ __launch_bounds__(256) void k1_gemm(const float* __restrict__ h,
                                               const float* __restrict__ W,
                                               const float* __restrict__ a,
                                               float* __restrict__ Wh,
                                               float* __restrict__ s1g,
                                               float* __restrict__ s2g) {
    __shared__ __align__(16) float hS[32][68];     // [k][m], pad 68 (16B-aligned rows)
    __shared__ __align__(16) float wS[32][128];    // [k][n]
    __shared__ float red[2][64][36];

    const int tid = threadIdx.x;
    const int tn  = tid & 31;    // cols 4*tn .. +3
    const int tm  = tid >> 5;    // rows 8*tm .. +7
    const int row0 = blockIdx.x * 64;

    // stage-load mapping
    const int h_r  = tid >> 2;          // 0..63
    const int h_c0 = (tid & 3) * 8;     // 0,8,16,24

    float acc[8][4];
#pragma unroll
    for (int m = 0; m < 8; ++m)
#pragma unroll
        for (int c = 0; c < 4; ++c) acc[m][c] = 0.f;

    float4 ha, hb, wreg[4];
    // prefetch kt=0
    ha = *(const float4*)&h[(size_t)(row0 + h_r) * FIN + h_c0];
    hb = *(const float4*)&h[(size_t)(row0 + h_r) * FIN + h_c0 + 4];
#pragma unroll
    for (int p = 0; p < 4; ++p) {
        int idx = p * 256 + tid, kW = idx >> 5, n4 = (idx & 31) * 4;
        wreg[p] = *(const float4*)&W[(size_t)kW * FO + n4];
    }

    for (int kt = 0; kt < FIN; kt += 32) {
        // registers -> LDS
        hS[h_c0 + 0][h_r] = ha.x; hS[h_c0 + 1][h_r] = ha.y;
        hS[h_c0 + 2][h_r] = ha.z; hS[h_c0 + 3][h_r] = ha.w;
        hS[h_c0 + 4][h_r] = hb.x; hS[h_c0 + 5][h_r] = hb.y;
        hS[h_c0 + 6][h_r] = hb.z; hS[h_c0 + 7][h_r] = hb.w;
#pragma unroll
        for (int p = 0; p < 4; ++p) {
            int idx = p * 256 + tid, kW = idx >> 5, n4 = (idx & 31) * 4;
            *(float4*)&wS[kW][n4] = wreg[p];
        }
        __syncthreads();

        // issue next tile's global loads
        if (kt + 32 < FIN) {
            ha = *(const float4*)&h[(size_t)(row0 + h_r) * FIN + kt + 32 + h_c0];
            hb = *(const float4*)&h[(size_t)(row0 + h_r) * FIN + kt + 32 + h_c0 + 4];
#pragma unroll
            for (int p = 0; p < 4; ++p) {
                int idx = p * 256 + tid, kW = idx >> 5, n4 = (idx & 31) * 4;
                wreg[p] = *(const float4*)&W[(size_t)(kt + 32 + kW) * FO + n4];
            }
        }

#pragma unroll 4
        for (int kk = 0; kk < 32; ++kk) {
            float4 h0 = *(float4*)&hS[kk][8 * tm];
            float4 h1 = *(float4*)&hS[kk][8 * tm + 4];
            float4 wv = *(float4*)&wS[kk][4 * tn];
            float hm[8] = {h0.x, h0.y, h0.z, h0.w, h1.x, h1.y, h1.z, h1.w};
            float wn4[4] = {wv.x, wv.y, wv.z, wv.w};
#pragma unroll
            for (int m = 0; m < 8; ++m)
#pragma unroll
                for (int c = 0; c < 4; ++c)
                    acc[m][c] += hm[m] * wn4[c];
        }
        __syncthreads();
    }

    // write Wh (b128 stores, 32 tn tile a full 512B row)
#pragma unroll
    for (int m = 0; m < 8; ++m) {
        float4 o = make_float4(acc[m][0], acc[m][1], acc[m][2], acc[m][3]);
        *(float4*)&Wh[(size_t)(row0 + 8 * tm + m) * FO + 4 * tn] = o;
    }

    // fused s1/s2
    float a1v[4], a2v[4];
#pragma unroll
    for (int c = 0; c < 4; ++c) {
        a1v[c] = a[4 * tn + c];
        a2v[c] = a[FO + 4 * tn + c];
    }
#pragma unroll
    for (int m = 0; m < 8; ++m) {
        float p1 = 0.f, p2 = 0.f;
#pragma unroll
        for (int c = 0; c < 4; ++c) {
            p1 += acc[m][c] * a1v[c];
            p2 += acc[m][c] * a2v[c];
        }
        red[0][8 * tm + m][tn] = p1;
        red[1][8 * tm + m][tn] = p2;
    }
    __syncthreads();
    if (tid < 128) {
        int arr = tid >> 6, li = tid & 63;
        float s = 0.f;
#pragma unroll
        for (int g = 0; g < 8; ++g) {
            float4 v = *(float4*)&red[arr][li][4 * g];
            s += v.x + v.y + v.z + v.w;
        }
        (arr ? s2g : s1g)[row0 + li] = s;
    }
}

// ---------------- K2a: brute-force rank + scatter + exps ----------------
// grid = B_*32 blocks, 512 threads; block ranks 64 elements, 8 threads/element.
__global__ __launch_bounds__(512) void k2a_rank(const float* __restrict__ s2g,
                                                float* __restrict__ ssort,
                                                int* __restrict__ sord,
                                                float* __restrict__ e2p,
                                                float* __restrict__ e2n) {
    __shared__ uint64_t keys[N_];   // 16 KB
    __shared__ int part[512];
    const int b = blockIdx.x >> 5, c = blockIdx.x & 31;
    const int tid = threadIdx.x;

    for (int t = tid; t < N_; t += 512) {
        unsigned u = __float_as_uint(s2g[b * N_ + t]);
        u = (u & 0x80000000u) ? ~u : (u | 0x80000000u);   // order-preserving map
        keys[t] = ((uint64_t)u << 16) | (unsigned)t;      // unique keys -> no ties
    }
    __syncthreads();

    const int le = tid & 63;
    const int e  = c * 64 + le;
    const int q  = tid >> 6;         // 0..7
    const uint64_t myk = keys[e];
    const uint64_t* kp = keys + q * 256;
    int cnt = 0;
#pragma unroll 8
    for (int kk = 0; kk < 256; ++kk) cnt += (int)(kp[kk] > myk);
    part[tid] = cnt;
    __syncthreads();

    if (tid < 64) {
        int rank = 0;
#pragma unroll
        for (int g = 0; g < 8; ++g) rank += part[tid + 64 * g];
        int ee = c * 64 + tid;
        float v = s2g[b * N_ + ee];
        ssort[b * N_ + rank] = v;
        sord[b * N_ + rank]  = ee;
        e2p[b * N_ + rank] = expf(v);
        e2n[b * N_ + rank] = expf(ALPHA * v);
    }
}

// ---------------- K2b: scalar scans + per-row cutoff (ILP searches) ----------------
__global__ __launch_bounds__(256) void k2b_scan(const float* __restrict__ ssort,
                                                const float* __restrict__ s1g,
                                                const float* __restrict__ e2p,
                                                const float* __restrict__ e2n,
                                                float2* __restrict__ DPN,
                                                int* __restrict__ kcut) {
    __shared__ float sv[N_];
    __shared__ float tp[256], tn[256];
    const int b = blockIdx.x, tid = threadIdx.x;
    const size_t base = (size_t)b * N_;

    float v[8], pv[8], nv[8], lp[8], ln[8];
    *(float4*)&v[0]  = *(const float4*)&ssort[base + tid * 8];
    *(float4*)&v[4]  = *(const float4*)&ssort[base + tid * 8 + 4];
    *(float4*)&pv[0] = *(const float4*)&e2p[base + tid * 8];
    *(float4*)&pv[4] = *(const float4*)&e2p[base + tid * 8 + 4];
    *(float4*)&nv[0] = *(const float4*)&e2n[base + tid * 8];
    *(float4*)&nv[4] = *(const float4*)&e2n[base + tid * 8 + 4];
    float ap = 0.f, an = 0.f;
#pragma unroll
    for (int j = 0; j < 8; ++j) {
        sv[tid * 8 + j] = v[j];
        ap += pv[j]; lp[j] = ap;
        an += nv[j]; ln[j] = an;
    }
    tp[tid] = ap; tn[tid] = an;
    __syncthreads();

    for (int off = 1; off < 256; off <<= 1) {
        float xp = tp[tid], xn = tn[tid];
        if (tid >= off) { xp += tp[tid - off]; xn += tn[tid - off]; }
        __syncthreads();
        tp[tid] = xp; tn[tid] = xn;
        __syncthreads();
    }
    float offp = (tid > 0) ? tp[tid - 1] : 0.f;
    float offn = (tid > 0) ? tn[tid - 1] : 0.f;
#pragma unroll
    for (int j = 0; j < 8; ++j) {
        DPN[base + tid * 8 + j] = make_float2(lp[j] + offp, ln[j] + offn);
    }

    // per-row cutoffs: 8 interleaved fixed-step binary searches (ILP)
    float tgt[8];
    int lo[8], hi[8];
#pragma unroll
    for (int r = 0; r < 8; ++r) {
        tgt[r] = -s1g[base + tid + 256 * r];
        lo[r] = 0; hi[r] = N_;
    }
#pragma unroll
    for (int step = 0; step < 12; ++step) {
#pragma unroll
        for (int r = 0; r < 8; ++r) {
            int mid = (lo[r] + hi[r]) >> 1;
            bool live = lo[r] < hi[r];
            float pv2 = sv[mid & (N_ - 1)];
            bool cc = live && (pv2 >= tgt[r]);
            lo[r] = cc ? mid + 1 : lo[r];
            hi[r] = (live && !cc) ? mid : hi[r];
        }
    }
#pragma unroll
    for (int r = 0; r < 8; ++r) kcut[base + tid + 256 * r] = lo[r];
}

// ---------------- K3: chunk-local vector prefix scans ----------------
// grid = B_*NCHUNK = 512 blocks, 512 threads: f = tid&127, q = tid>>7 owns 8 k's.
__global__ __launch_bounds__(512) void k3_scan(const float* __restrict__ Wh,
                                               const int* __restrict__ sord,
                                               const float* __restrict__ e2p,
                                               const float* __restrict__ e2n,
                                               float2* __restrict__ SPN,
                                               float2* __restrict__ CT) {
    __shared__ float2 qt[4][FO];
    const int b = blockIdx.x >> 6, ch = blockIdx.x & 63;
    const int tid = threadIdx.x;
    const int f = tid & 127, q = tid >> 7;
    const size_t base = (size_t)b * N_;
    const int ks = ch * CHUNK + q * 8;

    int ords[8]; float wp[8], wn[8], xv[8];
#pragma unroll
    for (int j = 0; j < 8; ++j) ords[j] = sord[base + ks + j];
#pragma unroll
    for (int j = 0; j < 8; ++j) { wp[j] = e2p[base + ks + j]; wn[j] = e2n[base + ks + j]; }
#pragma unroll
    for (int j = 0; j < 8; ++j) xv[j] = Wh[(base + ords[j]) * FO + f];

    float ap = 0.f, an = 0.f;
    float2 s[8];
#pragma unroll
    for (int j = 0; j < 8; ++j) {
        ap += wp[j] * xv[j];
        an += wn[j] * xv[j];
        s[j] = make_float2(ap, an);
    }
    qt[q][f] = make_float2(ap, an);
    __syncthreads();

    float2 t0 = qt[0][f], t1 = qt[1][f], t2 = qt[2][f];
    float op = 0.f, on = 0.f;
    if (q > 0) { op += t0.x; on += t0.y; }
    if (q > 1) { op += t1.x; on += t1.y; }
    if (q > 2) { op += t2.x; on += t2.y; }
#pragma unroll
    for (int j = 0; j < 8; ++j)
        SPN[(base + ks + j) * FO + f] = make_float2(s[j].x + op, s[j].y + on);
    if (q == 3)
        CT[((size_t)b * NCHUNK + ch) * FO + f] = make_float2(s[7].x + op, s[7].y + on);
}

// ---------------- K3b: per-batch chunk-offset scan in LDS ----------------
// 8 blocks, 256 threads
__global__ __launch_bounds__(256) void k3b_offs(const float2* __restrict__ CT,
                                                float2* __restrict__ OFFS,
                                                float* __restrict__ SNtot) {
    __shared__ float2 ct[NCHUNK][FO];            // 64 KB
    __shared__ float2 halfTot[2][FO];
    const int b = blockIdx.x, tid = threadIdx.x;

    for (int idx = tid; idx < NCHUNK * FO; idx += 256) {
        int c = idx >> 7, f = idx & 127;
        ct[c][f] = CT[((size_t)b * NCHUNK + c) * FO + f];
    }
    __syncthreads();

    const int f = tid & 127, hh = tid >> 7;
    float rp = 0.f, rn = 0.f;
    for (int c = hh * 32; c < hh * 32 + 32; ++c) {
        float2 t = ct[c][f];
        ct[c][f] = make_float2(rp, rn);          // exclusive, local to half
        rp += t.x; rn += t.y;
    }
    halfTot[hh][f] = make_float2(rp, rn);
    __syncthreads();

    float addP = hh ? halfTot[0][f].x : 0.f;
    float addN = hh ? halfTot[0][f].y : 0.f;
    for (int c = hh * 32; c < hh * 32 + 32; ++c) {
        float2 t = ct[c][f];
        OFFS[((size_t)b * NCHUNK + c) * FO + f] = make_float2(t.x + addP, t.y + addN);
    }
    if (tid < FO) SNtot[b * FO + tid] = halfTot[0][tid].y + halfTot[1][tid].y;
}

// ---------------- K4: combine + elu ----------------
// grid = B_*N_/2 blocks, 256 threads (2 rows x 128 f)
__global__ __launch_bounds__(256) void k4_final(const float* __restrict__ s1g,
                                                const int* __restrict__ kcut,
                                                const float2* __restrict__ DPN,
                                                const float2* __restrict__ SPN,
                                                const float2* __restrict__ OFFS,
                                                const float* __restrict__ SNtot,
                                                float* __restrict__ out) {
    const int rowg = blockIdx.x * 2 + (threadIdx.x >> 7);
    const int f = threadIdx.x & 127;
    const int b = rowg >> 11;
    const size_t base = (size_t)b * N_;

    const float s1v = s1g[rowg];
    const int k = kcut[rowg];

    const float ep1 = expf(s1v), en1 = expf(ALPHA * s1v);
    float dp = 0.f, dn = 0.f, sp = 0.f, sn = 0.f;
    if (k > 0) {
        float2 d = DPN[base + k - 1];
        dp = d.x; dn = d.y;
        int c = (k - 1) >> 5;   // CHUNK=32
        float2 s = SPN[(base + k - 1) * FO + f];
        float2 o = OFFS[((size_t)b * NCHUNK + c) * FO + f];
        sp = o.x + s.x;
        sn = o.y + s.y;
    }
    const float dnt = DPN[base + N_ - 1].y;
    const float snt = SNtot[b * FO + f];

    const float den = ep1 * dp + en1 * (dnt - dn);
    const float num = ep1 * sp + en1 * (snt - sn);
    const float o = num / den;
    out[(size_t)rowg * FO + f] = (o > 0.f) ? o : (expf(o) - 1.f);
}

// ---------------- launch ----------------
extern "C" void kernel_launch(void* const* d_in, const int* in_sizes, int n_in,
                              void* d_out, int out_size, void* d_ws, size_t ws_size,
                              hipStream_t stream) {
    const float* h = (const float*)d_in[0];
    const float* W = (const float*)d_in[1];
    const float* a = (const float*)d_in[2];
    float* out = (float*)d_out;
    float* ws = (float*)d_ws;

    float*  Wh    = ws + OFF_WH;
    float*  s1    = ws + OFF_S1;
    float*  s2    = ws + OFF_S2;
    float*  ssort = ws + OFF_SSORT;
    int*    sord  = (int*)(ws + OFF_SORD);
    float*  e2p   = ws + OFF_E2P;
    float*  e2n   = ws + OFF_E2N;
    float2* DPN   = (float2*)(ws + OFF_DPN);
    int*    kcut  = (int*)(ws + OFF_KCUT);
    float2* SPN   = (float2*)(ws + OFF_SPN);
    float2* OFFS  = (float2*)(ws + OFF_OFFS);
    float*  SNtot = ws + OFF_SNTOT;
    float2* CT    = (float2*)(ws + OFF_CT);

    k1_gemm<<<dim3(B_ * N_ / 64), dim3(256), 0, stream>>>(h, W, a, Wh, s1, s2);
    k2a_rank<<<dim3(B_ * 32), dim3(512), 0, stream>>>(s2, ssort, sord, e2p, e2n);
    k2b_scan<<<dim3(B_), dim3(256), 0, stream>>>(ssort, s1, e2p, e2n, DPN, kcut);
    k3_scan<<<dim3(B_ * NCHUNK), dim3(512), 0, stream>>>(Wh, sord, e2p, e2n, SPN, CT);
    k3b_offs<<<dim3(B_), dim3(256), 0, stream>>>(CT, OFFS, SNtot);
    k4_final<<<dim3(B_ * N_ / 2), dim3(256), 0, stream>>>(s1, kcut, DPN, SPN,
                                                          OFFS, SNtot, out);
}